// Round 1
// baseline (5586.448 us; speedup 1.0000x reference)
//
#include <hip/hip_runtime.h>

#define N_NODES 16384
#define N_GRAPHS 32
#define NPG 512
#define C 88
#define NL 6
#define NH 4
#define HD 22
#define EA 131072
#define EE 262144
#define EDIM 197
#define EEMB 8
#define PE_RAW 18
#define PE_DIM 10
#define XD 96
#define XF 78
#define BN_EPS 1e-5f
#define ATT_SCALE 0.21320071635561044f

// ---------------- edge attr embedding: wave per edge (A and E fused) -------
__global__ void k_edge_emb(const float* __restrict__ Aattr, const float* __restrict__ Eattr,
                           const float* __restrict__ W, float* __restrict__ Aemb,
                           float* __restrict__ Eemb) {
    int wid = (blockIdx.x * blockDim.x + threadIdx.x) >> 6;
    int lane = threadIdx.x & 63;
    if (wid >= EA + EE) return;
    const float* attr;
    float* out;
    if (wid < EA) { attr = Aattr + (size_t)wid * EDIM; out = Aemb + (size_t)wid * EEMB; }
    else { int e = wid - EA; attr = Eattr + (size_t)e * EDIM; out = Eemb + (size_t)e * EEMB; }
    float p[EEMB];
#pragma unroll
    for (int j = 0; j < EEMB; j++) p[j] = 0.f;
    for (int i = lane; i < EDIM; i += 64) {
        float a = attr[i];
#pragma unroll
        for (int j = 0; j < EEMB; j++) p[j] += a * W[i * EEMB + j];
    }
#pragma unroll
    for (int off = 32; off > 0; off >>= 1) {
#pragma unroll
        for (int j = 0; j < EEMB; j++) p[j] += __shfl_xor(p[j], off, 64);
    }
    if (lane < EEMB) {
        float v = 0.f;
#pragma unroll
        for (int j = 0; j < EEMB; j++) if (lane == j) v = p[j];
        out[lane] = v;
    }
}

// ---------------- per-column mean/rstd over rows ---------------------------
__global__ void k_colstats(const float* __restrict__ X, int ldx, int nrows,
                           float* __restrict__ mean, float* __restrict__ rstd) {
    int c = blockIdx.x;
    int t = threadIdx.x;
    float s = 0.f, s2 = 0.f;
    for (int r = t; r < nrows; r += 256) {
        float v = X[(size_t)r * ldx + c];
        s += v; s2 += v * v;
    }
    __shared__ float ls[256], ls2[256];
    ls[t] = s; ls2[t] = s2;
    __syncthreads();
    for (int off = 128; off > 0; off >>= 1) {
        if (t < off) { ls[t] += ls[t + off]; ls2[t] += ls2[t + off]; }
        __syncthreads();
    }
    if (t == 0) {
        float m = ls[0] / nrows;
        float var = ls2[0] / nrows - m * m;
        mean[c] = m;
        rstd[c] = rsqrtf(var + BN_EPS);
    }
}

// ---------------- build h0 = [x, bn(pe)@pe_w + pe_b] -----------------------
__global__ void k_build_h(const float* __restrict__ xd, const float* __restrict__ pe_mean,
                          const float* __restrict__ pe_rstd, const float* __restrict__ pe_g,
                          const float* __restrict__ pe_bt, const float* __restrict__ pe_w,
                          const float* __restrict__ pe_b, float* __restrict__ h) {
    int gid = blockIdx.x * blockDim.x + threadIdx.x;
    if (gid >= N_NODES * C) return;
    int n = gid / C, c = gid % C;
    float v;
    if (c < XF) {
        v = xd[(size_t)n * XD + c];
    } else {
        int j = c - XF;
        float acc = pe_b[j];
#pragma unroll
        for (int i = 0; i < PE_RAW; i++) {
            float pn = (xd[(size_t)n * XD + XF + i] - pe_mean[i]) * pe_rstd[i] * pe_g[i] + pe_bt[i];
            acc += pn * pe_w[i * PE_DIM + j];
        }
        v = acc;
    }
    h[gid] = v;
}

// ---------------- GINE edge message + scatter-add --------------------------
__global__ void k_gine_edge(const float* __restrict__ Aemb, const int* __restrict__ ei,
                            const float* __restrict__ h, const float* __restrict__ ew,
                            const float* __restrict__ eb, float* __restrict__ aggr) {
    long gid = (long)blockIdx.x * blockDim.x + threadIdx.x;
    if (gid >= (long)EA * C) return;
    int e = (int)(gid / C), c = (int)(gid % C);
    const float* emb = Aemb + (size_t)e * EEMB;
    float ea = eb[c];
#pragma unroll
    for (int j = 0; j < EEMB; j++) ea += emb[j] * ew[j * C + c];
    int s = ei[e], d = ei[EA + e];
    float msg = h[(size_t)s * C + c] + ea;
    msg = fmaxf(msg, 0.f);
    atomicAdd(&aggr[(size_t)d * C + c], msg);
}

// ---------------- u = relu((h+aggr)@w1 + b1) -------------------------------
__global__ void k_gine_a(const float* __restrict__ h, const float* __restrict__ aggr,
                         const float* __restrict__ w1, const float* __restrict__ b1,
                         float* __restrict__ u) {
    int gid = blockIdx.x * blockDim.x + threadIdx.x;
    if (gid >= N_NODES * C) return;
    int n = gid / C, c = gid % C;
    const float* hr = h + (size_t)n * C;
    const float* ar = aggr + (size_t)n * C;
    float acc = b1[c];
#pragma unroll 8
    for (int j = 0; j < C; j++) acc += (hr[j] + ar[j]) * w1[j * C + c];
    u[gid] = fmaxf(acc, 0.f);
}

// ---------------- OUT = X@W + b + R  (88->88) ------------------------------
__global__ void k_dense_res(const float* __restrict__ X, const float* __restrict__ R,
                            const float* __restrict__ W, const float* __restrict__ b,
                            float* __restrict__ OUT) {
    int gid = blockIdx.x * blockDim.x + threadIdx.x;
    if (gid >= N_NODES * C) return;
    int n = gid / C, c = gid % C;
    const float* xr = X + (size_t)n * C;
    float acc = b[c];
#pragma unroll 8
    for (int j = 0; j < C; j++) acc += xr[j] * W[j * C + c];
    OUT[gid] = acc + R[gid];
}

// ---------------- q,k,v projections ----------------------------------------
__global__ void k_qkv(const float* __restrict__ h,
                      const float* __restrict__ wq, const float* __restrict__ bq,
                      const float* __restrict__ wk, const float* __restrict__ bk,
                      const float* __restrict__ wv, const float* __restrict__ bv,
                      float* __restrict__ q, float* __restrict__ k, float* __restrict__ v) {
    int gid = blockIdx.x * blockDim.x + threadIdx.x;
    if (gid >= N_NODES * C) return;
    int n = gid / C, c = gid % C;
    const float* hr = h + (size_t)n * C;
    float aq = bq[c], ak = bk[c], av = bv[c];
#pragma unroll 8
    for (int j = 0; j < C; j++) {
        float hj = hr[j];
        aq += hj * wq[j * C + c];
        ak += hj * wk[j * C + c];
        av += hj * wv[j * C + c];
    }
    q[gid] = aq; k[gid] = ak; v[gid] = av;
}

// ---------------- flash attention: block per (graph, head, qtile) ----------
#define KCH 16
__global__ __launch_bounds__(128) void k_attn(const float* __restrict__ q,
                                              const float* __restrict__ kbuf,
                                              const float* __restrict__ vbuf,
                                              float* __restrict__ o) {
    int bx = blockIdx.x;
    int qt = bx & 3;
    int head = (bx >> 2) & 3;
    int g = bx >> 4;
    int t = threadIdx.x;
    int qnode = g * NPG + qt * 128 + t;
    const float* qr = q + (size_t)qnode * C + head * HD;
    float qreg[24], oreg[24];
#pragma unroll
    for (int d = 0; d < 24; d++) {
        qreg[d] = (d < HD) ? qr[d] * ATT_SCALE : 0.f;
        oreg[d] = 0.f;
    }
    float m = -1e30f, l = 0.f;
    __shared__ float Kt[64][24];
    __shared__ float Vt[64][24];
    for (int kt = 0; kt < NPG / 64; kt++) {
        __syncthreads();
        for (int idx = t; idx < 64 * HD; idx += 128) {
            int r = idx / HD, cc = idx % HD;
            int knode = g * NPG + kt * 64 + r;
            Kt[r][cc] = kbuf[(size_t)knode * C + head * HD + cc];
            Vt[r][cc] = vbuf[(size_t)knode * C + head * HD + cc];
        }
        for (int idx = t; idx < 64 * 2; idx += 128) {
            int r = idx >> 1, cc = HD + (idx & 1);
            Kt[r][cc] = 0.f; Vt[r][cc] = 0.f;
        }
        __syncthreads();
        for (int c0 = 0; c0 < 64; c0 += KCH) {
            float sc[KCH];
#pragma unroll
            for (int i = 0; i < KCH; i++) {
                float s = 0.f;
#pragma unroll
                for (int d = 0; d < 24; d++) s += qreg[d] * Kt[c0 + i][d];
                sc[i] = s;
            }
            float tmax = sc[0];
#pragma unroll
            for (int i = 1; i < KCH; i++) tmax = fmaxf(tmax, sc[i]);
            float newm = fmaxf(m, tmax);
            float alpha = __expf(m - newm);
            l *= alpha;
#pragma unroll
            for (int d = 0; d < 24; d++) oreg[d] *= alpha;
            m = newm;
#pragma unroll
            for (int i = 0; i < KCH; i++) {
                float p = __expf(sc[i] - m);
                l += p;
#pragma unroll
                for (int d = 0; d < 24; d++) oreg[d] += p * Vt[c0 + i][d];
            }
        }
    }
    float inv = 1.f / l;
    float* orow = o + (size_t)qnode * C + head * HD;
#pragma unroll
    for (int d = 0; d < HD; d++) orow[d] = oreg[d] * inv;
}

// ---------------- out3 = bn1(s1) + bn2(s2) ---------------------------------
__global__ void k_out3(const float* __restrict__ s1, const float* __restrict__ s2,
                       const float* __restrict__ m1, const float* __restrict__ r1,
                       const float* __restrict__ g1, const float* __restrict__ b1,
                       const float* __restrict__ m2, const float* __restrict__ r2,
                       const float* __restrict__ g2, const float* __restrict__ b2,
                       float* __restrict__ out3) {
    int gid = blockIdx.x * blockDim.x + threadIdx.x;
    if (gid >= N_NODES * C) return;
    int c = gid % C;
    float a = (s1[gid] - m1[c]) * r1[c] * g1[c] + b1[c];
    float b = (s2[gid] - m2[c]) * r2[c] * g2[c] + b2[c];
    out3[gid] = a + b;
}

// ---------------- u2 = relu(out3@mw1 + mb1)  (88->176) ---------------------
__global__ void k_mlp_a(const float* __restrict__ x, const float* __restrict__ w,
                        const float* __restrict__ b, float* __restrict__ u2) {
    int gid = blockIdx.x * blockDim.x + threadIdx.x;
    if (gid >= N_NODES * 176) return;
    int n = gid / 176, c = gid % 176;
    const float* xr = x + (size_t)n * C;
    float acc = b[c];
#pragma unroll 8
    for (int j = 0; j < C; j++) acc += xr[j] * w[j * 176 + c];
    u2[gid] = fmaxf(acc, 0.f);
}

// ---------------- s3 = out3 + u2@mw2 + mb2  (176->88) ----------------------
__global__ void k_mlp_b(const float* __restrict__ u2, const float* __restrict__ out3,
                        const float* __restrict__ w, const float* __restrict__ b,
                        float* __restrict__ s3) {
    int gid = blockIdx.x * blockDim.x + threadIdx.x;
    if (gid >= N_NODES * C) return;
    int n = gid / C, c = gid % C;
    const float* ur = u2 + (size_t)n * 176;
    float acc = b[c];
#pragma unroll 8
    for (int j = 0; j < 176; j++) acc += ur[j] * w[j * C + c];
    s3[gid] = acc + out3[gid];
}

// ---------------- h = bn3(s3) ----------------------------------------------
__global__ void k_bn_apply(const float* __restrict__ s, const float* __restrict__ m,
                           const float* __restrict__ r, const float* __restrict__ g,
                           const float* __restrict__ b, float* __restrict__ h) {
    int gid = blockIdx.x * blockDim.x + threadIdx.x;
    if (gid >= N_NODES * C) return;
    int c = gid % C;
    h[gid] = (s[gid] - m[c]) * r[c] * g[c] + b[c];
}

// ---------------- final edge MLP: wave per edge ----------------------------
__global__ void k_final(const float* __restrict__ h, const int* __restrict__ ei,
                        const float* __restrict__ Eemb, const float* __restrict__ w1,
                        const float* __restrict__ b1, const float* __restrict__ w2,
                        const float* __restrict__ b2, float* __restrict__ out) {
    int wid = (blockIdx.x * blockDim.x + threadIdx.x) >> 6;
    int lane = threadIdx.x & 63;
    if (wid >= EE) return;
    int se = ei[wid], de = ei[EE + wid];
    const float* hs = h + (size_t)se * C;
    const float* hd = h + (size_t)de * C;
    const float* em = Eemb + (size_t)wid * EEMB;
    int c1 = lane;
    int c2 = lane + 64;
    bool has2 = (c2 < C);
    float a1 = b1[c1];
    float a2 = has2 ? b1[c2] : 0.f;
    for (int j = 0; j < C; j++) {
        float zj = hs[j];
        a1 += zj * w1[j * C + c1];
        if (has2) a2 += zj * w1[j * C + c2];
    }
    for (int j = 0; j < C; j++) {
        float zj = hd[j];
        a1 += zj * w1[(C + j) * C + c1];
        if (has2) a2 += zj * w1[(C + j) * C + c2];
    }
#pragma unroll
    for (int j = 0; j < EEMB; j++) {
        float zj = em[j];
        a1 += zj * w1[(2 * C + j) * C + c1];
        if (has2) a2 += zj * w1[(2 * C + j) * C + c2];
    }
    a1 = fmaxf(a1, 0.f);
    a2 = fmaxf(a2, 0.f);
    float part = a1 * w2[c1] + (has2 ? a2 * w2[c2] : 0.f);
#pragma unroll
    for (int off = 32; off > 0; off >>= 1) part += __shfl_xor(part, off, 64);
    if (lane == 0) out[wid] = part + b2[0];
}

// ===========================================================================
extern "C" void kernel_launch(void* const* d_in, const int* in_sizes, int n_in,
                              void* d_out, int out_size, void* d_ws, size_t ws_size,
                              hipStream_t stream) {
    const float* xd = (const float*)d_in[0];
    const int* A_ei = (const int*)d_in[1];
    const float* Aattr = (const float*)d_in[2];
    const int* E_ei = (const int*)d_in[3];
    const float* Eattr = (const float*)d_in[4];
    const float* AW = (const float*)d_in[6];
    const float* pe_g = (const float*)d_in[7];
    const float* pe_bt = (const float*)d_in[8];
    const float* pe_w = (const float*)d_in[9];
    const float* pe_b = (const float*)d_in[10];
    const float* gine_ew = (const float*)d_in[11];
    const float* gine_eb = (const float*)d_in[12];
    const float* gine_w1 = (const float*)d_in[13];
    const float* gine_b1 = (const float*)d_in[14];
    const float* gine_w2 = (const float*)d_in[15];
    const float* gine_b2 = (const float*)d_in[16];
    const float* wq = (const float*)d_in[17];
    const float* wk = (const float*)d_in[18];
    const float* wv = (const float*)d_in[19];
    const float* wo = (const float*)d_in[20];
    const float* bq = (const float*)d_in[21];
    const float* bk = (const float*)d_in[22];
    const float* bv = (const float*)d_in[23];
    const float* bo = (const float*)d_in[24];
    const float* n1g = (const float*)d_in[25];
    const float* n2g = (const float*)d_in[26];
    const float* n3g = (const float*)d_in[27];
    const float* n1b = (const float*)d_in[28];
    const float* n2b = (const float*)d_in[29];
    const float* n3b = (const float*)d_in[30];
    const float* mw1 = (const float*)d_in[31];
    const float* mb1 = (const float*)d_in[32];
    const float* mw2 = (const float*)d_in[33];
    const float* mb2 = (const float*)d_in[34];
    const float* ew1 = (const float*)d_in[35];
    const float* eb1 = (const float*)d_in[36];
    const float* ew2 = (const float*)d_in[37];
    const float* eb2 = (const float*)d_in[38];

    float* ws = (float*)d_ws;
    size_t off = 0;
    auto alloc = [&](size_t n) { float* p = ws + off; off += n; return p; };
    float* Aemb = alloc((size_t)EA * EEMB);
    float* Eemb = alloc((size_t)EE * EEMB);
    float* h = alloc((size_t)N_NODES * C);
    float* aggr = alloc((size_t)N_NODES * C);
    float* u = alloc((size_t)N_NODES * C);
    float* s1 = alloc((size_t)N_NODES * C);   // also reused as s3
    float* qb = alloc((size_t)N_NODES * C);
    float* kb = alloc((size_t)N_NODES * C);
    float* vb = alloc((size_t)N_NODES * C);
    float* ob = alloc((size_t)N_NODES * C);
    float* s2 = alloc((size_t)N_NODES * C);
    float* out3 = alloc((size_t)N_NODES * C);
    float* u2 = alloc((size_t)N_NODES * 176);
    float* stats = alloc(1024);
    float* pe_mean = stats;
    float* pe_rstd = stats + 32;
    float* m1 = stats + 64, *r1 = stats + 160;
    float* m2 = stats + 256, *r2 = stats + 352;
    float* m3 = stats + 448, *r3 = stats + 544;

    const int NT = 256;
    const int nc_blocks = (N_NODES * C + NT - 1) / NT;

    // --- prologue ---
    k_edge_emb<<<((EA + EE) * 64 + NT - 1) / NT, NT, 0, stream>>>(Aattr, Eattr, AW, Aemb, Eemb);
    k_colstats<<<PE_RAW, NT, 0, stream>>>(xd + XF, XD, N_NODES, pe_mean, pe_rstd);
    k_build_h<<<nc_blocks, NT, 0, stream>>>(xd, pe_mean, pe_rstd, pe_g, pe_bt, pe_w, pe_b, h);

    // --- layers ---
    for (int l = 0; l < NL; l++) {
        const float* ew = gine_ew + (size_t)l * EEMB * C;
        const float* eb = gine_eb + (size_t)l * C;
        const float* w1 = gine_w1 + (size_t)l * C * C;
        const float* b1 = gine_b1 + (size_t)l * C;
        const float* w2 = gine_w2 + (size_t)l * C * C;
        const float* b2 = gine_b2 + (size_t)l * C;
        const float* lwq = wq + (size_t)l * C * C;
        const float* lwk = wk + (size_t)l * C * C;
        const float* lwv = wv + (size_t)l * C * C;
        const float* lwo = wo + (size_t)l * C * C;
        const float* lbq = bq + (size_t)l * C;
        const float* lbk = bk + (size_t)l * C;
        const float* lbv = bv + (size_t)l * C;
        const float* lbo = bo + (size_t)l * C;
        const float* l1g = n1g + (size_t)l * C;
        const float* l1b = n1b + (size_t)l * C;
        const float* l2g = n2g + (size_t)l * C;
        const float* l2b = n2b + (size_t)l * C;
        const float* l3g = n3g + (size_t)l * C;
        const float* l3b = n3b + (size_t)l * C;
        const float* lmw1 = mw1 + (size_t)l * C * 176;
        const float* lmb1 = mb1 + (size_t)l * 176;
        const float* lmw2 = mw2 + (size_t)l * 176 * C;
        const float* lmb2 = mb2 + (size_t)l * C;

        hipMemsetAsync(aggr, 0, (size_t)N_NODES * C * sizeof(float), stream);
        k_gine_edge<<<(int)(((long)EA * C + NT - 1) / NT), NT, 0, stream>>>(Aemb, A_ei, h, ew, eb, aggr);
        k_gine_a<<<nc_blocks, NT, 0, stream>>>(h, aggr, w1, b1, u);
        k_dense_res<<<nc_blocks, NT, 0, stream>>>(u, h, w2, b2, s1);
        k_colstats<<<C, NT, 0, stream>>>(s1, C, N_NODES, m1, r1);
        k_qkv<<<nc_blocks, NT, 0, stream>>>(h, lwq, lbq, lwk, lbk, lwv, lbv, qb, kb, vb);
        k_attn<<<N_GRAPHS * NH * 4, 128, 0, stream>>>(qb, kb, vb, ob);
        k_dense_res<<<nc_blocks, NT, 0, stream>>>(ob, h, lwo, lbo, s2);
        k_colstats<<<C, NT, 0, stream>>>(s2, C, N_NODES, m2, r2);
        k_out3<<<nc_blocks, NT, 0, stream>>>(s1, s2, m1, r1, l1g, l1b, m2, r2, l2g, l2b, out3);
        k_mlp_a<<<(N_NODES * 176 + NT - 1) / NT, NT, 0, stream>>>(out3, lmw1, lmb1, u2);
        k_mlp_b<<<nc_blocks, NT, 0, stream>>>(u2, out3, lmw2, lmb2, s1);
        k_colstats<<<C, NT, 0, stream>>>(s1, C, N_NODES, m3, r3);
        k_bn_apply<<<nc_blocks, NT, 0, stream>>>(s1, m3, r3, l3g, l3b, h);
    }

    // --- epilogue: edge MLP ---
    k_final<<<(EE * 64 + NT - 1) / NT, NT, 0, stream>>>(h, E_ei, Eemb, ew1, eb1, ew2, eb2,
                                                        (float*)d_out);
}

// Round 2
// 4442.605 us; speedup vs baseline: 1.2575x; 1.2575x over previous
//
#include <hip/hip_runtime.h>

#define N_NODES 16384
#define N_GRAPHS 32
#define NPG 512
#define C 88
#define NL 6
#define NH 4
#define HD 22
#define EA 131072
#define EE 262144
#define EDIM 197
#define EEMB 8
#define PE_RAW 18
#define PE_DIM 10
#define XD 96
#define XF 78
#define BN_EPS 1e-5f
#define ATT_SCALE 0.21320071635561044f

// ---------------- edge attr embedding: wave per edge (A and E fused) -------
__global__ void k_edge_emb(const float* __restrict__ Aattr, const float* __restrict__ Eattr,
                           const float* __restrict__ W, float* __restrict__ Aemb,
                           float* __restrict__ Eemb) {
    int wid = (blockIdx.x * blockDim.x + threadIdx.x) >> 6;
    int lane = threadIdx.x & 63;
    if (wid >= EA + EE) return;
    const float* attr;
    float* out;
    if (wid < EA) { attr = Aattr + (size_t)wid * EDIM; out = Aemb + (size_t)wid * EEMB; }
    else { int e = wid - EA; attr = Eattr + (size_t)e * EDIM; out = Eemb + (size_t)e * EEMB; }
    float p[EEMB];
#pragma unroll
    for (int j = 0; j < EEMB; j++) p[j] = 0.f;
    for (int i = lane; i < EDIM; i += 64) {
        float a = attr[i];
#pragma unroll
        for (int j = 0; j < EEMB; j++) p[j] += a * W[i * EEMB + j];
    }
#pragma unroll
    for (int off = 32; off > 0; off >>= 1) {
#pragma unroll
        for (int j = 0; j < EEMB; j++) p[j] += __shfl_xor(p[j], off, 64);
    }
    if (lane < EEMB) {
        float v = 0.f;
#pragma unroll
        for (int j = 0; j < EEMB; j++) if (lane == j) v = p[j];
        out[lane] = v;
    }
}

// ---------------- per-column mean/rstd over rows ---------------------------
__global__ void k_colstats(const float* __restrict__ X, int ldx, int nrows,
                           float* __restrict__ mean, float* __restrict__ rstd) {
    int c = blockIdx.x;
    int t = threadIdx.x;
    float s = 0.f, s2 = 0.f;
    for (int r = t; r < nrows; r += 256) {
        float v = X[(size_t)r * ldx + c];
        s += v; s2 += v * v;
    }
    __shared__ float ls[256], ls2[256];
    ls[t] = s; ls2[t] = s2;
    __syncthreads();
    for (int off = 128; off > 0; off >>= 1) {
        if (t < off) { ls[t] += ls[t + off]; ls2[t] += ls2[t + off]; }
        __syncthreads();
    }
    if (t == 0) {
        float m = ls[0] / nrows;
        float var = ls2[0] / nrows - m * m;
        mean[c] = m;
        rstd[c] = rsqrtf(var + BN_EPS);
    }
}

// ---------------- build h0 = [x, bn(pe)@pe_w + pe_b] -----------------------
__global__ void k_build_h(const float* __restrict__ xd, const float* __restrict__ pe_mean,
                          const float* __restrict__ pe_rstd, const float* __restrict__ pe_g,
                          const float* __restrict__ pe_bt, const float* __restrict__ pe_w,
                          const float* __restrict__ pe_b, float* __restrict__ h) {
    int gid = blockIdx.x * blockDim.x + threadIdx.x;
    if (gid >= N_NODES * C) return;
    int n = gid / C, c = gid % C;
    float v;
    if (c < XF) {
        v = xd[(size_t)n * XD + c];
    } else {
        int j = c - XF;
        float acc = pe_b[j];
#pragma unroll
        for (int i = 0; i < PE_RAW; i++) {
            float pn = (xd[(size_t)n * XD + XF + i] - pe_mean[i]) * pe_rstd[i] * pe_g[i] + pe_bt[i];
            acc += pn * pe_w[i * PE_DIM + j];
        }
        v = acc;
    }
    h[gid] = v;
}

// ---------------- GINE edge message + scatter-add --------------------------
__global__ void k_gine_edge(const float* __restrict__ Aemb, const int* __restrict__ ei,
                            const float* __restrict__ h, const float* __restrict__ ew,
                            const float* __restrict__ eb, float* __restrict__ aggr) {
    long gid = (long)blockIdx.x * blockDim.x + threadIdx.x;
    if (gid >= (long)EA * C) return;
    int e = (int)(gid / C), c = (int)(gid % C);
    const float* emb = Aemb + (size_t)e * EEMB;
    float ea = eb[c];
#pragma unroll
    for (int j = 0; j < EEMB; j++) ea += emb[j] * ew[j * C + c];
    int s = ei[e], d = ei[EA + e];
    float msg = h[(size_t)s * C + c] + ea;
    msg = fmaxf(msg, 0.f);
    atomicAdd(&aggr[(size_t)d * C + c], msg);
}

// ---------------- u = relu((h+aggr)@w1 + b1) -------------------------------
__global__ void k_gine_a(const float* __restrict__ h, const float* __restrict__ aggr,
                         const float* __restrict__ w1, const float* __restrict__ b1,
                         float* __restrict__ u) {
    int gid = blockIdx.x * blockDim.x + threadIdx.x;
    if (gid >= N_NODES * C) return;
    int n = gid / C, c = gid % C;
    const float* hr = h + (size_t)n * C;
    const float* ar = aggr + (size_t)n * C;
    float acc = b1[c];
#pragma unroll 8
    for (int j = 0; j < C; j++) acc += (hr[j] + ar[j]) * w1[j * C + c];
    u[gid] = fmaxf(acc, 0.f);
}

// ---------------- OUT = X@W + b + R  (88->88) ------------------------------
__global__ void k_dense_res(const float* __restrict__ X, const float* __restrict__ R,
                            const float* __restrict__ W, const float* __restrict__ b,
                            float* __restrict__ OUT) {
    int gid = blockIdx.x * blockDim.x + threadIdx.x;
    if (gid >= N_NODES * C) return;
    int n = gid / C, c = gid % C;
    const float* xr = X + (size_t)n * C;
    float acc = b[c];
#pragma unroll 8
    for (int j = 0; j < C; j++) acc += xr[j] * W[j * C + c];
    OUT[gid] = acc + R[gid];
}

// ---------------- q,k,v projections ----------------------------------------
__global__ void k_qkv(const float* __restrict__ h,
                      const float* __restrict__ wq, const float* __restrict__ bq,
                      const float* __restrict__ wk, const float* __restrict__ bk,
                      const float* __restrict__ wv, const float* __restrict__ bv,
                      float* __restrict__ q, float* __restrict__ k, float* __restrict__ v) {
    int gid = blockIdx.x * blockDim.x + threadIdx.x;
    if (gid >= N_NODES * C) return;
    int n = gid / C, c = gid % C;
    const float* hr = h + (size_t)n * C;
    float aq = bq[c], ak = bk[c], av = bv[c];
#pragma unroll 8
    for (int j = 0; j < C; j++) {
        float hj = hr[j];
        aq += hj * wq[j * C + c];
        ak += hj * wk[j * C + c];
        av += hj * wv[j * C + c];
    }
    q[gid] = aq; k[gid] = ak; v[gid] = av;
}

// ---------------- flash attention: block per (graph, head, qtile) ----------
#define KCH 16
__global__ __launch_bounds__(128) void k_attn(const float* __restrict__ q,
                                              const float* __restrict__ kbuf,
                                              const float* __restrict__ vbuf,
                                              float* __restrict__ o) {
    int bx = blockIdx.x;
    int qt = bx & 3;
    int head = (bx >> 2) & 3;
    int g = bx >> 4;
    int t = threadIdx.x;
    int qnode = g * NPG + qt * 128 + t;
    const float* qr = q + (size_t)qnode * C + head * HD;
    float qreg[24], oreg[24];
#pragma unroll
    for (int d = 0; d < 24; d++) {
        qreg[d] = (d < HD) ? qr[d] * ATT_SCALE : 0.f;
        oreg[d] = 0.f;
    }
    float m = -1e30f, l = 0.f;
    __shared__ float Kt[64][24];
    __shared__ float Vt[64][24];
    for (int kt = 0; kt < NPG / 64; kt++) {
        __syncthreads();
        for (int idx = t; idx < 64 * HD; idx += 128) {
            int r = idx / HD, cc = idx % HD;
            int knode = g * NPG + kt * 64 + r;
            Kt[r][cc] = kbuf[(size_t)knode * C + head * HD + cc];
            Vt[r][cc] = vbuf[(size_t)knode * C + head * HD + cc];
        }
        for (int idx = t; idx < 64 * 2; idx += 128) {
            int r = idx >> 1, cc = HD + (idx & 1);
            Kt[r][cc] = 0.f; Vt[r][cc] = 0.f;
        }
        __syncthreads();
        for (int c0 = 0; c0 < 64; c0 += KCH) {
            float sc[KCH];
#pragma unroll
            for (int i = 0; i < KCH; i++) {
                float s = 0.f;
#pragma unroll
                for (int d = 0; d < 24; d++) s += qreg[d] * Kt[c0 + i][d];
                sc[i] = s;
            }
            float tmax = sc[0];
#pragma unroll
            for (int i = 1; i < KCH; i++) tmax = fmaxf(tmax, sc[i]);
            float newm = fmaxf(m, tmax);
            float alpha = __expf(m - newm);
            l *= alpha;
#pragma unroll
            for (int d = 0; d < 24; d++) oreg[d] *= alpha;
            m = newm;
#pragma unroll
            for (int i = 0; i < KCH; i++) {
                float p = __expf(sc[i] - m);
                l += p;
#pragma unroll
                for (int d = 0; d < 24; d++) oreg[d] += p * Vt[c0 + i][d];
            }
        }
    }
    float inv = 1.f / l;
    float* orow = o + (size_t)qnode * C + head * HD;
#pragma unroll
    for (int d = 0; d < HD; d++) orow[d] = oreg[d] * inv;
}

// ---------------- out3 = bn1(s1) + bn2(s2) ---------------------------------
__global__ void k_out3(const float* __restrict__ s1, const float* __restrict__ s2,
                       const float* __restrict__ m1, const float* __restrict__ r1,
                       const float* __restrict__ g1, const float* __restrict__ b1,
                       const float* __restrict__ m2, const float* __restrict__ r2,
                       const float* __restrict__ g2, const float* __restrict__ b2,
                       float* __restrict__ out3) {
    int gid = blockIdx.x * blockDim.x + threadIdx.x;
    if (gid >= N_NODES * C) return;
    int c = gid % C;
    float a = (s1[gid] - m1[c]) * r1[c] * g1[c] + b1[c];
    float b = (s2[gid] - m2[c]) * r2[c] * g2[c] + b2[c];
    out3[gid] = a + b;
}

// ---------------- u2 = relu(out3@mw1 + mb1)  (88->176) ---------------------
__global__ void k_mlp_a(const float* __restrict__ x, const float* __restrict__ w,
                        const float* __restrict__ b, float* __restrict__ u2) {
    int gid = blockIdx.x * blockDim.x + threadIdx.x;
    if (gid >= N_NODES * 176) return;
    int n = gid / 176, c = gid % 176;
    const float* xr = x + (size_t)n * C;
    float acc = b[c];
#pragma unroll 8
    for (int j = 0; j < C; j++) acc += xr[j] * w[j * 176 + c];
    u2[gid] = fmaxf(acc, 0.f);
}

// ---------------- s3 = out3 + u2@mw2 + mb2  (176->88) ----------------------
__global__ void k_mlp_b(const float* __restrict__ u2, const float* __restrict__ out3,
                        const float* __restrict__ w, const float* __restrict__ b,
                        float* __restrict__ s3) {
    int gid = blockIdx.x * blockDim.x + threadIdx.x;
    if (gid >= N_NODES * C) return;
    int n = gid / C, c = gid % C;
    const float* ur = u2 + (size_t)n * 176;
    float acc = b[c];
#pragma unroll 8
    for (int j = 0; j < 176; j++) acc += ur[j] * w[j * C + c];
    s3[gid] = acc + out3[gid];
}

// ---------------- h = bn3(s3) ----------------------------------------------
__global__ void k_bn_apply(const float* __restrict__ s, const float* __restrict__ m,
                           const float* __restrict__ r, const float* __restrict__ g,
                           const float* __restrict__ b, float* __restrict__ h) {
    int gid = blockIdx.x * blockDim.x + threadIdx.x;
    if (gid >= N_NODES * C) return;
    int c = gid % C;
    h[gid] = (s[gid] - m[c]) * r[c] * g[c] + b[c];
}

// ---------------- P = h@W1_src + b1, Q = h@W1_dst (edge-MLP factorization) -
__global__ void k_dense_pq(const float* __restrict__ h, const float* __restrict__ w1,
                           const float* __restrict__ b1,
                           float* __restrict__ P, float* __restrict__ Q) {
    int gid = blockIdx.x * blockDim.x + threadIdx.x;
    if (gid >= N_NODES * C) return;
    int n = gid / C, c = gid % C;
    const float* hr = h + (size_t)n * C;
    const float* ws = w1;              // rows 0..87   (src part)
    const float* wd = w1 + (size_t)C * C;  // rows 88..175 (dst part)
    float ap = b1[c], aq = 0.f;
#pragma unroll 8
    for (int j = 0; j < C; j++) {
        float hj = hr[j];
        ap += hj * ws[j * C + c];
        aq += hj * wd[j * C + c];
    }
    P[gid] = ap; Q[gid] = aq;
}

// ---------------- final: logit = relu(P[se]+Q[de]+Eemb@W1_emb) . w2 + b2 ---
__global__ void k_final2(const float* __restrict__ P, const float* __restrict__ Q,
                         const int* __restrict__ ei, const float* __restrict__ Eemb,
                         const float* __restrict__ w1emb, const float* __restrict__ w2,
                         const float* __restrict__ b2, float* __restrict__ out) {
    int wid = (blockIdx.x * blockDim.x + threadIdx.x) >> 6;
    int lane = threadIdx.x & 63;
    if (wid >= EE) return;
    int se = ei[wid], de = ei[EE + wid];
    const float* ps = P + (size_t)se * C;
    const float* qd = Q + (size_t)de * C;
    const float* em = Eemb + (size_t)wid * EEMB;
    float e0 = em[0], e1 = em[1], e2 = em[2], e3 = em[3];
    float e4 = em[4], e5 = em[5], e6 = em[6], e7 = em[7];
    int c1 = lane, c2 = lane + 64;
    bool has2 = (c2 < C);
    float a1 = ps[c1] + qd[c1];
    float a2 = has2 ? (ps[c2] + qd[c2]) : 0.f;
    a1 += e0 * w1emb[0 * C + c1] + e1 * w1emb[1 * C + c1] + e2 * w1emb[2 * C + c1] +
          e3 * w1emb[3 * C + c1] + e4 * w1emb[4 * C + c1] + e5 * w1emb[5 * C + c1] +
          e6 * w1emb[6 * C + c1] + e7 * w1emb[7 * C + c1];
    if (has2)
        a2 += e0 * w1emb[0 * C + c2] + e1 * w1emb[1 * C + c2] + e2 * w1emb[2 * C + c2] +
              e3 * w1emb[3 * C + c2] + e4 * w1emb[4 * C + c2] + e5 * w1emb[5 * C + c2] +
              e6 * w1emb[6 * C + c2] + e7 * w1emb[7 * C + c2];
    a1 = fmaxf(a1, 0.f);
    a2 = fmaxf(a2, 0.f);
    float part = a1 * w2[c1] + (has2 ? a2 * w2[c2] : 0.f);
#pragma unroll
    for (int off = 32; off > 0; off >>= 1) part += __shfl_xor(part, off, 64);
    if (lane == 0) out[wid] = part + b2[0];
}

// ===========================================================================
extern "C" void kernel_launch(void* const* d_in, const int* in_sizes, int n_in,
                              void* d_out, int out_size, void* d_ws, size_t ws_size,
                              hipStream_t stream) {
    const float* xd = (const float*)d_in[0];
    const int* A_ei = (const int*)d_in[1];
    const float* Aattr = (const float*)d_in[2];
    const int* E_ei = (const int*)d_in[3];
    const float* Eattr = (const float*)d_in[4];
    const float* AW = (const float*)d_in[6];
    const float* pe_g = (const float*)d_in[7];
    const float* pe_bt = (const float*)d_in[8];
    const float* pe_w = (const float*)d_in[9];
    const float* pe_b = (const float*)d_in[10];
    const float* gine_ew = (const float*)d_in[11];
    const float* gine_eb = (const float*)d_in[12];
    const float* gine_w1 = (const float*)d_in[13];
    const float* gine_b1 = (const float*)d_in[14];
    const float* gine_w2 = (const float*)d_in[15];
    const float* gine_b2 = (const float*)d_in[16];
    const float* wq = (const float*)d_in[17];
    const float* wk = (const float*)d_in[18];
    const float* wv = (const float*)d_in[19];
    const float* wo = (const float*)d_in[20];
    const float* bq = (const float*)d_in[21];
    const float* bk = (const float*)d_in[22];
    const float* bv = (const float*)d_in[23];
    const float* bo = (const float*)d_in[24];
    const float* n1g = (const float*)d_in[25];
    const float* n2g = (const float*)d_in[26];
    const float* n3g = (const float*)d_in[27];
    const float* n1b = (const float*)d_in[28];
    const float* n2b = (const float*)d_in[29];
    const float* n3b = (const float*)d_in[30];
    const float* mw1 = (const float*)d_in[31];
    const float* mb1 = (const float*)d_in[32];
    const float* mw2 = (const float*)d_in[33];
    const float* mb2 = (const float*)d_in[34];
    const float* ew1 = (const float*)d_in[35];
    const float* eb1 = (const float*)d_in[36];
    const float* ew2 = (const float*)d_in[37];
    const float* eb2 = (const float*)d_in[38];

    float* ws = (float*)d_ws;
    size_t off = 0;
    auto alloc = [&](size_t n) { float* p = ws + off; off += n; return p; };
    float* Aemb = alloc((size_t)EA * EEMB);
    float* Eemb = alloc((size_t)EE * EEMB);
    float* h = alloc((size_t)N_NODES * C);
    float* aggr = alloc((size_t)N_NODES * C);
    float* u = alloc((size_t)N_NODES * C);
    float* s1 = alloc((size_t)N_NODES * C);   // also reused as s3
    float* qb = alloc((size_t)N_NODES * C);   // reused as P after layer loop
    float* kb = alloc((size_t)N_NODES * C);   // reused as Q after layer loop
    float* vb = alloc((size_t)N_NODES * C);
    float* ob = alloc((size_t)N_NODES * C);
    float* s2 = alloc((size_t)N_NODES * C);
    float* out3 = alloc((size_t)N_NODES * C);
    float* u2 = alloc((size_t)N_NODES * 176);
    float* stats = alloc(1024);
    float* pe_mean = stats;
    float* pe_rstd = stats + 32;
    float* m1 = stats + 64, *r1 = stats + 160;
    float* m2 = stats + 256, *r2 = stats + 352;
    float* m3 = stats + 448, *r3 = stats + 544;

    const int NT = 256;
    const int nc_blocks = (N_NODES * C + NT - 1) / NT;

    // --- prologue ---
    k_edge_emb<<<((EA + EE) * 64 + NT - 1) / NT, NT, 0, stream>>>(Aattr, Eattr, AW, Aemb, Eemb);
    k_colstats<<<PE_RAW, NT, 0, stream>>>(xd + XF, XD, N_NODES, pe_mean, pe_rstd);
    k_build_h<<<nc_blocks, NT, 0, stream>>>(xd, pe_mean, pe_rstd, pe_g, pe_bt, pe_w, pe_b, h);

    // --- layers ---
    for (int l = 0; l < NL; l++) {
        const float* ew = gine_ew + (size_t)l * EEMB * C;
        const float* eb = gine_eb + (size_t)l * C;
        const float* w1 = gine_w1 + (size_t)l * C * C;
        const float* b1 = gine_b1 + (size_t)l * C;
        const float* w2 = gine_w2 + (size_t)l * C * C;
        const float* b2 = gine_b2 + (size_t)l * C;
        const float* lwq = wq + (size_t)l * C * C;
        const float* lwk = wk + (size_t)l * C * C;
        const float* lwv = wv + (size_t)l * C * C;
        const float* lwo = wo + (size_t)l * C * C;
        const float* lbq = bq + (size_t)l * C;
        const float* lbk = bk + (size_t)l * C;
        const float* lbv = bv + (size_t)l * C;
        const float* lbo = bo + (size_t)l * C;
        const float* l1g = n1g + (size_t)l * C;
        const float* l1b = n1b + (size_t)l * C;
        const float* l2g = n2g + (size_t)l * C;
        const float* l2b = n2b + (size_t)l * C;
        const float* l3g = n3g + (size_t)l * C;
        const float* l3b = n3b + (size_t)l * C;
        const float* lmw1 = mw1 + (size_t)l * C * 176;
        const float* lmb1 = mb1 + (size_t)l * 176;
        const float* lmw2 = mw2 + (size_t)l * 176 * C;
        const float* lmb2 = mb2 + (size_t)l * C;

        hipMemsetAsync(aggr, 0, (size_t)N_NODES * C * sizeof(float), stream);
        k_gine_edge<<<(int)(((long)EA * C + NT - 1) / NT), NT, 0, stream>>>(Aemb, A_ei, h, ew, eb, aggr);
        k_gine_a<<<nc_blocks, NT, 0, stream>>>(h, aggr, w1, b1, u);
        k_dense_res<<<nc_blocks, NT, 0, stream>>>(u, h, w2, b2, s1);
        k_colstats<<<C, NT, 0, stream>>>(s1, C, N_NODES, m1, r1);
        k_qkv<<<nc_blocks, NT, 0, stream>>>(h, lwq, lbq, lwk, lbk, lwv, lbv, qb, kb, vb);
        k_attn<<<N_GRAPHS * NH * 4, 128, 0, stream>>>(qb, kb, vb, ob);
        k_dense_res<<<nc_blocks, NT, 0, stream>>>(ob, h, lwo, lbo, s2);
        k_colstats<<<C, NT, 0, stream>>>(s2, C, N_NODES, m2, r2);
        k_out3<<<nc_blocks, NT, 0, stream>>>(s1, s2, m1, r1, l1g, l1b, m2, r2, l2g, l2b, out3);
        k_mlp_a<<<(N_NODES * 176 + NT - 1) / NT, NT, 0, stream>>>(out3, lmw1, lmb1, u2);
        k_mlp_b<<<nc_blocks, NT, 0, stream>>>(u2, out3, lmw2, lmb2, s1);
        k_colstats<<<C, NT, 0, stream>>>(s1, C, N_NODES, m3, r3);
        k_bn_apply<<<nc_blocks, NT, 0, stream>>>(s1, m3, r3, l3g, l3b, h);
    }

    // --- epilogue: factored edge MLP ---
    // P = h @ ew1[0:88]   + eb1 ;  Q = h @ ew1[88:176]
    k_dense_pq<<<nc_blocks, NT, 0, stream>>>(h, ew1, eb1, qb, kb);
    k_final2<<<(EE * 64 + NT - 1) / NT, NT, 0, stream>>>(qb, kb, E_ei, Eemb,
                                                         ew1 + (size_t)2 * C * C, ew2, eb2,
                                                         (float*)d_out);
}